// Round 1
// baseline (3823.164 us; speedup 1.0000x reference)
//
#include <hip/hip_runtime.h>

#define M_ROWS 32768   // B*N
#define DIM    512
#define KCB    8192    // codebook size
#define NSPLIT 4
#define CPS    (KCB/NSPLIT)   // 2048 cols per split
#define MT     128     // rows per block
#define NTILE  128     // cols per tile
#define KC     32      // k chunk
#define LDP    132     // padded LDS row stride (floats)

// ---------------------------------------------------------------- row norms
__global__ void __launch_bounds__(256) vq_rownorm(const float* __restrict__ z,
                                                  float* __restrict__ A) {
    int row  = blockIdx.x * 4 + (threadIdx.x >> 6);
    int lane = threadIdx.x & 63;
    const float* zr = z + (size_t)row * DIM;
    float4 a = *(const float4*)(zr + lane * 4);
    float4 b = *(const float4*)(zr + 256 + lane * 4);
    float s = a.x*a.x + a.y*a.y + a.z*a.z + a.w*a.w
            + b.x*b.x + b.y*b.y + b.z*b.z + b.w*b.w;
    #pragma unroll
    for (int off = 32; off > 0; off >>= 1) s += __shfl_down(s, off, 64);
    if (lane == 0) A[row] = s;
}

// ------------------------------------------- fused distance + running argmin
__global__ void __launch_bounds__(256, 3)
vq_dist(const float* __restrict__ z, const float* __restrict__ cb,
        const float* __restrict__ A, float* __restrict__ candD,
        int* __restrict__ candI) {
    __shared__ float zs[KC][LDP];
    __shared__ float cs[KC][LDP];
    const int t  = threadIdx.x;
    const int tx = t & 15;        // column group (16)
    const int ty = t >> 4;        // row group (16)
    const int sp = blockIdx.x & (NSPLIT - 1);
    const int rowBase = (int)(blockIdx.x >> 2) * MT;
    const int colBase = sp * CPS;

    float Arow[8];
    #pragma unroll
    for (int r = 0; r < 8; ++r) Arow[r] = A[rowBase + ty * 8 + r];

    float bestD[8]; int bestI[8];
    #pragma unroll
    for (int r = 0; r < 8; ++r) { bestD[r] = 1e30f; bestI[r] = 0; }

    for (int nt = 0; nt < CPS / NTILE; ++nt) {
        const int ncol0 = colBase + nt * NTILE;
        float acc[8][8];
        #pragma unroll
        for (int r = 0; r < 8; ++r)
            #pragma unroll
            for (int c = 0; c < 8; ++c) acc[r][c] = 0.0f;

        for (int kc = 0; kc < DIM; kc += KC) {
            // stage z-tile and cb-tile, transposed to K-major [kk][row]
            #pragma unroll
            for (int j = 0; j < 4; ++j) {
                int lin = j * 256 + t;          // 0..1023
                int row = lin >> 3;             // 0..127
                int k4  = (lin & 7) << 2;       // 0..28
                float4 v = *(const float4*)(z  + (size_t)(rowBase + row) * DIM + kc + k4);
                zs[k4 + 0][row] = v.x; zs[k4 + 1][row] = v.y;
                zs[k4 + 2][row] = v.z; zs[k4 + 3][row] = v.w;
                float4 w = *(const float4*)(cb + (size_t)(ncol0 + row) * DIM + kc + k4);
                cs[k4 + 0][row] = w.x; cs[k4 + 1][row] = w.y;
                cs[k4 + 2][row] = w.z; cs[k4 + 3][row] = w.w;
            }
            __syncthreads();
            #pragma unroll 4
            for (int kk = 0; kk < KC; ++kk) {
                float4 a0 = *(const float4*)&zs[kk][ty * 8];
                float4 a1 = *(const float4*)&zs[kk][ty * 8 + 4];
                float4 b0 = *(const float4*)&cs[kk][tx * 8];
                float4 b1 = *(const float4*)&cs[kk][tx * 8 + 4];
                float av[8] = {a0.x, a0.y, a0.z, a0.w, a1.x, a1.y, a1.z, a1.w};
                float bv[8] = {b0.x, b0.y, b0.z, b0.w, b1.x, b1.y, b1.z, b1.w};
                #pragma unroll
                for (int r = 0; r < 8; ++r)
                    #pragma unroll
                    for (int c = 0; c < 8; ++c)
                        acc[r][c] = fmaf(av[r], bv[c], acc[r][c]);
            }
            __syncthreads();
        }
        // fused argmin for this 128-col tile: d = fl(A - 2C), first-index tiebreak
        #pragma unroll
        for (int r = 0; r < 8; ++r) {
            float bd = 1e30f; int bi = 0x7fffffff;
            #pragma unroll
            for (int c = 0; c < 8; ++c) {
                float d   = Arow[r] - 2.0f * acc[r][c];
                int   col = ncol0 + tx * 8 + c;
                if (d < bd || (d == bd && col < bi)) { bd = d; bi = col; }
            }
            #pragma unroll
            for (int m = 1; m < 16; m <<= 1) {
                float od = __shfl_xor(bd, m, 16);
                int   oi = __shfl_xor(bi, m, 16);
                if (od < bd || (od == bd && oi < bi)) { bd = od; bi = oi; }
            }
            if (bd < bestD[r] || (bd == bestD[r] && bi < bestI[r])) {
                bestD[r] = bd; bestI[r] = bi;
            }
        }
    }
    if (tx == 0) {
        #pragma unroll
        for (int r = 0; r < 8; ++r) {
            int row = rowBase + ty * 8 + r;
            candD[row * NSPLIT + sp] = bestD[r];
            candI[row * NSPLIT + sp] = bestI[r];
        }
    }
}

// ------------------------- combine split candidates, gather, STE out, loss
__global__ void __launch_bounds__(256)
vq_gather(const float* __restrict__ z, const float* __restrict__ cb,
          const float* __restrict__ candD, const int* __restrict__ candI,
          float* __restrict__ outQ, float* __restrict__ outIdx,
          double* __restrict__ lossRow) {
    int w = threadIdx.x >> 6, lane = threadIdx.x & 63;
    int row = blockIdx.x * 4 + w;
    float bd = 1e30f; int bi = 0x7fffffff;
    #pragma unroll
    for (int s2 = 0; s2 < NSPLIT; ++s2) {
        float d = candD[row * NSPLIT + s2];
        int   i = candI[row * NSPLIT + s2];
        if (d < bd || (d == bd && i < bi)) { bd = d; bi = i; }
    }
    const float* q  = cb + (size_t)bi * DIM;
    const float* zr = z  + (size_t)row * DIM;
    float* o = outQ + (size_t)row * DIM;
    double ls = 0.0;
    #pragma unroll
    for (int j = 0; j < 2; ++j) {
        int off = j * 256 + lane * 4;
        float4 qv = *(const float4*)(q  + off);
        float4 zv = *(const float4*)(zr + off);
        float t0 = qv.x - zv.x, t1 = qv.y - zv.y;
        float t2 = qv.z - zv.z, t3 = qv.w - zv.w;
        float4 ov = { zv.x + t0, zv.y + t1, zv.z + t2, zv.w + t3 }; // fl(z + fl(q-z))
        *(float4*)(o + off) = ov;
        ls += (double)t0 * t0 + (double)t1 * t1
            + (double)t2 * t2 + (double)t3 * t3;
    }
    #pragma unroll
    for (int off = 32; off > 0; off >>= 1) ls += __shfl_down(ls, off, 64);
    if (lane == 0) { lossRow[row] = ls; outIdx[row] = (float)bi; }
}

// ------------------------------------------------------------ loss finalize
__global__ void __launch_bounds__(256)
vq_loss_final(const double* __restrict__ lossRow, float* __restrict__ outLoss) {
    __shared__ double sm[256];
    double s = 0.0;
    for (int i = threadIdx.x; i < M_ROWS; i += 256) s += lossRow[i];
    sm[threadIdx.x] = s;
    __syncthreads();
    for (int st = 128; st > 0; st >>= 1) {
        if (threadIdx.x < st) sm[threadIdx.x] += sm[threadIdx.x + st];
        __syncthreads();
    }
    if (threadIdx.x == 0)
        outLoss[0] = (float)(1.25 * sm[0] / (double)((size_t)M_ROWS * DIM));
}

extern "C" void kernel_launch(void* const* d_in, const int* in_sizes, int n_in,
                              void* d_out, int out_size, void* d_ws, size_t ws_size,
                              hipStream_t stream) {
    const float* z  = (const float*)d_in[0];
    const float* cb = (const float*)d_in[1];

    float* out     = (float*)d_out;
    float* outQ    = out;                                  // 16777216 floats
    float* outIdx  = out + (size_t)M_ROWS * DIM;           // 32768 floats
    float* outLoss = out + (size_t)M_ROWS * DIM + M_ROWS;  // 1 float

    char* ws = (char*)d_ws;
    float*  A       = (float*)ws;                                    // 128 KB
    float*  candD   = (float*)(ws + (size_t)M_ROWS * 4);             // 512 KB
    int*    candI   = (int*)  (ws + (size_t)M_ROWS * 4 + (size_t)M_ROWS * NSPLIT * 4);
    double* lossRow = (double*)(ws + (size_t)M_ROWS * 4 + 2 * (size_t)M_ROWS * NSPLIT * 4);

    hipLaunchKernelGGL(vq_rownorm, dim3(M_ROWS / 4), dim3(256), 0, stream, z, A);
    hipLaunchKernelGGL(vq_dist, dim3((M_ROWS / MT) * NSPLIT), dim3(256), 0, stream,
                       z, cb, A, candD, candI);
    hipLaunchKernelGGL(vq_gather, dim3(M_ROWS / 4), dim3(256), 0, stream,
                       z, cb, candD, candI, outQ, outIdx, lossRow);
    hipLaunchKernelGGL(vq_loss_final, dim3(1), dim3(256), 0, stream, lossRow, outLoss);
}

// Round 2
// 1299.322 us; speedup vs baseline: 2.9424x; 2.9424x over previous
//
#include <hip/hip_runtime.h>

#define M_ROWS 32768
#define DIM    512
#define KCB    8192
#define BM     256
#define BN     256
#define KCH    32

typedef _Float16 f16x8 __attribute__((ext_vector_type(8)));
typedef _Float16 f16x4 __attribute__((ext_vector_type(4)));
typedef float    f32x16 __attribute__((ext_vector_type(16)));
typedef unsigned long long u64;

#define AS1(p) ((const __attribute__((address_space(1))) void*)(p))
#define AS3(p) ((__attribute__((address_space(3))) void*)(p))

// ---------------------------------------------------------------- fp16 split
__global__ void __launch_bounds__(256) vq_split(const float* __restrict__ x,
                                                _Float16* __restrict__ hi,
                                                _Float16* __restrict__ lo,
                                                float scale, int n4) {
    int i = blockIdx.x * 256 + threadIdx.x;
    if (i >= n4) return;
    float4 v = ((const float4*)x)[i];
    float a = v.x * scale, b = v.y * scale, c = v.z * scale, d = v.w * scale;
    _Float16 h0 = (_Float16)a, h1 = (_Float16)b, h2 = (_Float16)c, h3 = (_Float16)d;
    f16x4 hv = {h0, h1, h2, h3};
    f16x4 lv = {(_Float16)(a - (float)h0), (_Float16)(b - (float)h1),
                (_Float16)(c - (float)h2), (_Float16)(d - (float)h3)};
    ((f16x4*)hi)[i] = hv;
    ((f16x4*)lo)[i] = lv;
}

// ---------------------------------------------------------------- row norms (identical to round-1)
__global__ void __launch_bounds__(256) vq_rownorm(const float* __restrict__ z,
                                                  float* __restrict__ A) {
    int row  = blockIdx.x * 4 + (threadIdx.x >> 6);
    int lane = threadIdx.x & 63;
    const float* zr = z + (size_t)row * DIM;
    float4 a = *(const float4*)(zr + lane * 4);
    float4 b = *(const float4*)(zr + 256 + lane * 4);
    float s = a.x*a.x + a.y*a.y + a.z*a.z + a.w*a.w
            + b.x*b.x + b.y*b.y + b.z*b.z + b.w*b.w;
    #pragma unroll
    for (int off = 32; off > 0; off >>= 1) s += __shfl_down(s, off, 64);
    if (lane == 0) A[row] = s;
}

// ------------------------------------------- MFMA split-GEMM + top-2 select
__global__ void __launch_bounds__(512, 2)
vq_gemm(const _Float16* __restrict__ zh, const _Float16* __restrict__ zl,
        const _Float16* __restrict__ eh, const _Float16* __restrict__ el,
        const float* __restrict__ A, u64* __restrict__ cand) {
    __shared__ _Float16 ldsbuf[32768];   // 64 KB: zh|zl|eh|el planes, 16 KB each
    _Float16* Lzh = ldsbuf;
    _Float16* Lzl = ldsbuf + 8192;
    _Float16* Leh = ldsbuf + 16384;
    _Float16* Lel = ldsbuf + 24576;

    const int tid  = threadIdx.x;
    const int lane = tid & 63;
    const int wid  = tid >> 6;
    const int wr   = wid >> 1;       // 0..3 -> 64-row strip
    const int wc   = wid & 1;        // 0..1 -> 128-col half
    const int rowb = (int)blockIdx.x >> 5;
    const int colb = (int)blockIdx.x & 31;
    const int rowBase = rowb * BM;
    const int colBase = colb * BN;

    f32x16 acc[2][4];
    #pragma unroll
    for (int rt = 0; rt < 2; ++rt)
        #pragma unroll
        for (int ct = 0; ct < 4; ++ct) acc[rt][ct] = (f32x16)0.0f;

    // staging geometry: 64 gll instrs of 1KB; n = wid*8+g; dest = lds + n*1024
    const int rr = (lane >> 1);            // row within 32-group
    const int kh = (lane & 1) << 3;        // k half offset (0 or 8)

    for (int kc = 0; kc < DIM; kc += KCH) {
        __syncthreads();
        #pragma unroll
        for (int g = 0; g < 8; ++g) {
            int n    = (wid << 3) | g;
            int grp  = (n >> 1) & 7;
            int ks   = n & 1;
            int r    = (grp << 5) + rr;
            int k    = kc + (ks << 4) + kh;
            const _Float16* src;
            if      (n < 16) src = zh + ((size_t)(rowBase + r) << 9) + k;
            else if (n < 32) src = zl + ((size_t)(rowBase + r) << 9) + k;
            else if (n < 48) src = eh + ((size_t)(colBase + r) << 9) + k;
            else             src = el + ((size_t)(colBase + r) << 9) + k;
            __builtin_amdgcn_global_load_lds(AS1(src),
                AS3((char*)ldsbuf + (n << 10)), 16, 0, 0);
        }
        __syncthreads();   // compiler drains vmcnt before barrier

        const int foff = ((lane & 31) << 4) + ((lane >> 5) << 3);  // halves
        #pragma unroll
        for (int ks = 0; ks < 2; ++ks) {
            f16x8 ah[2], al[2];
            #pragma unroll
            for (int rt = 0; rt < 2; ++rt) {
                int rg = wr * 2 + rt;
                ah[rt] = *(const f16x8*)(Lzh + ((rg * 2 + ks) << 9) + foff);
                al[rt] = *(const f16x8*)(Lzl + ((rg * 2 + ks) << 9) + foff);
            }
            #pragma unroll
            for (int ct = 0; ct < 4; ++ct) {
                int cg = wc * 4 + ct;
                f16x8 bh = *(const f16x8*)(Leh + ((cg * 2 + ks) << 9) + foff);
                f16x8 bl = *(const f16x8*)(Lel + ((cg * 2 + ks) << 9) + foff);
                #pragma unroll
                for (int rt = 0; rt < 2; ++rt) {
                    acc[rt][ct] = __builtin_amdgcn_mfma_f32_32x32x16_f16(ah[rt], bh, acc[rt][ct], 0, 0, 0);
                    acc[rt][ct] = __builtin_amdgcn_mfma_f32_32x32x16_f16(ah[rt], bl, acc[rt][ct], 0, 0, 0);
                    acc[rt][ct] = __builtin_amdgcn_mfma_f32_32x32x16_f16(al[rt], bh, acc[rt][ct], 0, 0, 0);
                }
            }
        }
    }

    // epilogue: d = A - acc/2048, per-row top-2 over this wave's 128 cols
    __syncthreads();
    float* As = (float*)ldsbuf;           // reuse LDS
    if (tid < BM) As[tid] = A[rowBase + tid];
    __syncthreads();

    const int slab = colb * 2 + wc;       // 0..63
    #pragma unroll
    for (int rt = 0; rt < 2; ++rt) {
        #pragma unroll
        for (int r = 0; r < 16; ++r) {
            int rowInTile = (r & 3) + ((r >> 2) << 3) + ((lane >> 5) << 2);
            int row_l = wr * 64 + rt * 32 + rowInTile;
            float Arow = As[row_l];
            u64 b1 = ~0ull, b2 = ~0ull;
            #pragma unroll
            for (int ct = 0; ct < 4; ++ct) {
                float d = Arow - acc[rt][ct][r] * (1.0f / 2048.0f);
                int col = colBase + wc * 128 + ct * 32 + (lane & 31);
                u64 p = ((u64)__float_as_uint(d) << 32) | (unsigned)col;
                if (p < b1) { b2 = b1; b1 = p; } else if (p < b2) b2 = p;
            }
            #pragma unroll
            for (int m = 1; m < 32; m <<= 1) {
                u64 o1 = __shfl_xor(b1, m);
                u64 o2 = __shfl_xor(b2, m);
                u64 lo = b1 < o1 ? b1 : o1;
                u64 hi = b1 < o1 ? o1 : b1;
                u64 so = b2 < o2 ? b2 : o2;
                b1 = lo;
                b2 = hi < so ? hi : so;
            }
            if ((lane & 31) == 0) {
                size_t base = ((size_t)(rowBase + row_l) << 7) + (slab << 1);
                cand[base]     = b1;
                cand[base + 1] = b2;
            }
        }
    }
}

// ---------------- refine: exact fp32 chain (round-1 semantics) on survivors
__global__ void __launch_bounds__(256)
vq_refine(const float* __restrict__ z, const float* __restrict__ cb,
          const float* __restrict__ A, const u64* __restrict__ cand,
          int* __restrict__ bestIdx) {
    __shared__ float zs[4][DIM];
    __shared__ int   sc[4][128];
    int w = threadIdx.x >> 6, lane = threadIdx.x & 63;
    int row = blockIdx.x * 4 + w;

    const float* zr = z + (size_t)row * DIM;
    *(float4*)&zs[w][lane * 4]       = *(const float4*)(zr + lane * 4);
    *(float4*)&zs[w][256 + lane * 4] = *(const float4*)(zr + 256 + lane * 4);

    const u64* cr = cand + ((size_t)row << 7);
    u64 c0 = cr[lane * 2], c1 = cr[lane * 2 + 1];
    u64 mn = c0 < c1 ? c0 : c1;
    #pragma unroll
    for (int m = 32; m > 0; m >>= 1) { u64 o = __shfl_xor(mn, m); if (o < mn) mn = o; }
    float minD = __uint_as_float((unsigned)(mn >> 32));
    float thr = minD + 2e-4f;
    bool s0 = __uint_as_float((unsigned)(c0 >> 32)) <= thr;
    bool s1 = __uint_as_float((unsigned)(c1 >> 32)) <= thr;
    u64 m0 = __ballot(s0), m1 = __ballot(s1);
    u64 below = ((u64)1 << lane) - 1;
    int n0 = __popcll(m0);
    if (s0) sc[w][__popcll(m0 & below)]      = (int)(unsigned)c0;
    if (s1) sc[w][n0 + __popcll(m1 & below)] = (int)(unsigned)c1;
    int ns = n0 + __popcll(m1);
    __syncthreads();

    float Arow = A[row];
    u64 best = ~0ull;
    for (int j = lane; j < ns; j += 64) {
        int col = sc[w][j];
        const float* e = cb + (size_t)col * DIM;
        float acc2 = 0.0f;
        for (int k = 0; k < DIM; ++k) acc2 = fmaf(zs[w][k], e[k], acc2);
        float d = Arow - 2.0f * acc2;
        u64 p = ((u64)__float_as_uint(d) << 32) | (unsigned)col;
        if (p < best) best = p;
    }
    #pragma unroll
    for (int m = 32; m > 0; m >>= 1) { u64 o = __shfl_xor(best, m); if (o < best) best = o; }
    if (lane == 0) bestIdx[row] = (int)(unsigned)best;
}

// ------------------------- gather, STE out, loss rows (round-1 semantics)
__global__ void __launch_bounds__(256)
vq_gather(const float* __restrict__ z, const float* __restrict__ cb,
          const int* __restrict__ bestIdx, float* __restrict__ outQ,
          float* __restrict__ outIdx, double* __restrict__ lossRow) {
    int w = threadIdx.x >> 6, lane = threadIdx.x & 63;
    int row = blockIdx.x * 4 + w;
    int bi = bestIdx[row];
    const float* q  = cb + (size_t)bi * DIM;
    const float* zr = z  + (size_t)row * DIM;
    float* o = outQ + (size_t)row * DIM;
    double ls = 0.0;
    #pragma unroll
    for (int j = 0; j < 2; ++j) {
        int off = j * 256 + lane * 4;
        float4 qv = *(const float4*)(q  + off);
        float4 zv = *(const float4*)(zr + off);
        float t0 = qv.x - zv.x, t1 = qv.y - zv.y;
        float t2 = qv.z - zv.z, t3 = qv.w - zv.w;
        float4 ov = { zv.x + t0, zv.y + t1, zv.z + t2, zv.w + t3 };
        *(float4*)(o + off) = ov;
        ls += (double)t0 * t0 + (double)t1 * t1
            + (double)t2 * t2 + (double)t3 * t3;
    }
    #pragma unroll
    for (int off = 32; off > 0; off >>= 1) ls += __shfl_down(ls, off, 64);
    if (lane == 0) { lossRow[row] = ls; outIdx[row] = (float)bi; }
}

__global__ void __launch_bounds__(256)
vq_loss_final(const double* __restrict__ lossRow, float* __restrict__ outLoss) {
    __shared__ double sm[256];
    double s = 0.0;
    for (int i = threadIdx.x; i < M_ROWS; i += 256) s += lossRow[i];
    sm[threadIdx.x] = s;
    __syncthreads();
    for (int st = 128; st > 0; st >>= 1) {
        if (threadIdx.x < st) sm[threadIdx.x] += sm[threadIdx.x + st];
        __syncthreads();
    }
    if (threadIdx.x == 0)
        outLoss[0] = (float)(1.25 * sm[0] / (double)((size_t)M_ROWS * DIM));
}

extern "C" void kernel_launch(void* const* d_in, const int* in_sizes, int n_in,
                              void* d_out, int out_size, void* d_ws, size_t ws_size,
                              hipStream_t stream) {
    const float* z  = (const float*)d_in[0];
    const float* cb = (const float*)d_in[1];

    float* out     = (float*)d_out;
    float* outQ    = out;
    float* outIdx  = out + (size_t)M_ROWS * DIM;
    float* outLoss = out + (size_t)M_ROWS * DIM + M_ROWS;

    // z planes live in d_out scratch (overwritten later by gather)
    _Float16* zh = (_Float16*)d_out;
    _Float16* zl = zh + (size_t)M_ROWS * DIM;

    char* ws = (char*)d_ws;
    float*  A       = (float*)ws;            ws += (size_t)M_ROWS * 4;
    double* lossRow = (double*)ws;           ws += (size_t)M_ROWS * 8;
    int*    bestIdx = (int*)ws;              ws += (size_t)M_ROWS * 4;
    _Float16* eh    = (_Float16*)ws;         ws += (size_t)KCB * DIM * 2;
    _Float16* el    = (_Float16*)ws;         ws += (size_t)KCB * DIM * 2;
    u64*    cand    = (u64*)ws;              // 32768*128*8 = 33.5 MB

    hipLaunchKernelGGL(vq_split, dim3(M_ROWS * DIM / 4 / 256), dim3(256), 0, stream,
                       z, zh, zl, 1.0f, M_ROWS * DIM / 4);
    hipLaunchKernelGGL(vq_split, dim3(KCB * DIM / 4 / 256), dim3(256), 0, stream,
                       cb, eh, el, 4096.0f, KCB * DIM / 4);
    hipLaunchKernelGGL(vq_rownorm, dim3(M_ROWS / 4), dim3(256), 0, stream, z, A);
    hipLaunchKernelGGL(vq_gemm, dim3((M_ROWS / BM) * (KCB / BN)), dim3(512), 0, stream,
                       zh, zl, eh, el, A, cand);
    hipLaunchKernelGGL(vq_refine, dim3(M_ROWS / 4), dim3(256), 0, stream,
                       z, cb, A, cand, bestIdx);
    hipLaunchKernelGGL(vq_gather, dim3(M_ROWS / 4), dim3(256), 0, stream,
                       z, cb, bestIdx, outQ, outIdx, lossRow);
    hipLaunchKernelGGL(vq_loss_final, dim3(1), dim3(256), 0, stream, lossRow, outLoss);
}

// Round 3
// 716.668 us; speedup vs baseline: 5.3346x; 1.8130x over previous
//
#include <hip/hip_runtime.h>

#define M_ROWS 32768
#define DIM    512
#define KCB    8192
#define BM     256
#define BN     256
#define KCH    32
#define NITER  (DIM / KCH)   // 16

typedef _Float16 f16x8 __attribute__((ext_vector_type(8)));
typedef _Float16 f16x4 __attribute__((ext_vector_type(4)));
typedef float    f32x16 __attribute__((ext_vector_type(16)));
typedef unsigned long long u64;

#define AS1(p) ((const __attribute__((address_space(1))) void*)(p))
#define AS3(p) ((__attribute__((address_space(3))) void*)(p))

// ------------------------------------------------ fp16 hi-plane conversion
__global__ void __launch_bounds__(256) vq_split_hi(const float* __restrict__ x,
                                                   _Float16* __restrict__ hi,
                                                   float scale, int n4) {
    int i = blockIdx.x * 256 + threadIdx.x;
    if (i >= n4) return;
    float4 v = ((const float4*)x)[i];
    f16x4 hv = {(_Float16)(v.x * scale), (_Float16)(v.y * scale),
                (_Float16)(v.z * scale), (_Float16)(v.w * scale)};
    ((f16x4*)hi)[i] = hv;
}

// ---------------------------------------------------------------- row norms
__global__ void __launch_bounds__(256) vq_rownorm(const float* __restrict__ z,
                                                  float* __restrict__ A) {
    int row  = blockIdx.x * 4 + (threadIdx.x >> 6);
    int lane = threadIdx.x & 63;
    const float* zr = z + (size_t)row * DIM;
    float4 a = *(const float4*)(zr + lane * 4);
    float4 b = *(const float4*)(zr + 256 + lane * 4);
    float s = a.x*a.x + a.y*a.y + a.z*a.z + a.w*a.w
            + b.x*b.x + b.y*b.y + b.z*b.z + b.w*b.w;
    #pragma unroll
    for (int off = 32; off > 0; off >>= 1) s += __shfl_down(s, off, 64);
    if (lane == 0) A[row] = s;
}

// ----------------- single-product f16 MFMA GEMM (2-phase dbuf) + top-2 select
__global__ void __launch_bounds__(512, 2)
vq_gemm(const _Float16* __restrict__ zh, const _Float16* __restrict__ eh,
        const float* __restrict__ A, u64* __restrict__ cand) {
    __shared__ _Float16 ldsbuf[32768];   // 64 KB: 2 buffers x (zh 16KB | eh 16KB)

    const int tid  = threadIdx.x;
    const int lane = tid & 63;
    const int wid  = tid >> 6;
    const int wr   = wid >> 1;       // 0..3 -> 64-row strip
    const int wc   = wid & 1;        // 0..1 -> 128-col half
    const int rowBase = ((int)blockIdx.x >> 5) * BM;
    const int colBase = ((int)blockIdx.x & 31) * BN;

    f32x16 acc[2][4];
    #pragma unroll
    for (int rt = 0; rt < 2; ++rt)
        #pragma unroll
        for (int ct = 0; ct < 4; ++ct) acc[rt][ct] = (f32x16)0.0f;

    const int rr = (lane >> 1);            // row within 32-group
    const int kh = (lane & 1) << 3;        // k half offset (0 or 8)

    // stage 32 chunks of 1KB into buffer `buf` for k-chunk `t` (4 gll per wave)
    auto stage = [&](int buf, int t) {
        int kc = t * KCH;
        #pragma unroll
        for (int g = 0; g < 4; ++g) {
            int n     = (wid << 2) | g;    // 0..31
            int m     = n & 15;
            int grp   = m >> 1;
            int ks    = m & 1;
            int r     = (grp << 5) + rr;
            int k     = kc + (ks << 4) + kh;
            const _Float16* src = (n < 16)
                ? zh + ((size_t)(rowBase + r) << 9) + k
                : eh + ((size_t)(colBase + r) << 9) + k;
            __builtin_amdgcn_global_load_lds(AS1(src),
                AS3((char*)ldsbuf + (buf << 15) + (n << 10)), 16, 0, 0);
        }
    };

    stage(0, 0);
    __syncthreads();

    const int foff = ((lane & 31) << 4) + ((lane >> 5) << 3);
    int cur = 0;
    for (int t = 0; t < NITER; ++t) {
        if (t + 1 < NITER) stage(cur ^ 1, t + 1);
        const _Float16* Lz = ldsbuf + (cur << 14);          // halves
        const _Float16* Le = ldsbuf + (cur << 14) + 8192;
        #pragma unroll
        for (int ks = 0; ks < 2; ++ks) {
            f16x8 a[2];
            #pragma unroll
            for (int rt = 0; rt < 2; ++rt) {
                int rg = wr * 2 + rt;
                a[rt] = *(const f16x8*)(Lz + ((rg * 2 + ks) << 9) + foff);
            }
            #pragma unroll
            for (int ct = 0; ct < 4; ++ct) {
                int cg = wc * 4 + ct;
                f16x8 b = *(const f16x8*)(Le + ((cg * 2 + ks) << 9) + foff);
                #pragma unroll
                for (int rt = 0; rt < 2; ++rt)
                    acc[rt][ct] = __builtin_amdgcn_mfma_f32_32x32x16_f16(a[rt], b, acc[rt][ct], 0, 0, 0);
            }
        }
        __syncthreads();   // drains vmcnt (stage t+1) + lgkm, one barrier/iter
        cur ^= 1;
    }

    // epilogue: d = A - acc/2048, per-row top-2 over this wave's 128 cols
    float* As = (float*)ldsbuf;
    if (tid < BM) As[tid] = A[rowBase + tid];
    __syncthreads();

    const int slab = ((int)blockIdx.x & 31) * 2 + wc;   // 0..63
    #pragma unroll
    for (int rt = 0; rt < 2; ++rt) {
        #pragma unroll
        for (int r = 0; r < 16; ++r) {
            int rowInTile = (r & 3) + ((r >> 2) << 3) + ((lane >> 5) << 2);
            int row_l = wr * 64 + rt * 32 + rowInTile;
            float Arow = As[row_l];
            u64 b1 = ~0ull, b2 = ~0ull;
            #pragma unroll
            for (int ct = 0; ct < 4; ++ct) {
                float d = Arow - acc[rt][ct][r] * (1.0f / 2048.0f);
                int col = colBase + wc * 128 + ct * 32 + (lane & 31);
                u64 p = ((u64)__float_as_uint(d) << 32) | (unsigned)col;
                if (p < b1) { b2 = b1; b1 = p; } else if (p < b2) b2 = p;
            }
            #pragma unroll
            for (int m = 1; m < 32; m <<= 1) {
                u64 o1 = __shfl_xor(b1, m);
                u64 o2 = __shfl_xor(b2, m);
                u64 lo = b1 < o1 ? b1 : o1;
                u64 hi = b1 < o1 ? o1 : b1;
                u64 so = b2 < o2 ? b2 : o2;
                b1 = lo;
                b2 = hi < so ? hi : so;
            }
            if ((lane & 31) == 0) {
                size_t base = ((size_t)(rowBase + row_l) << 7) + (slab << 1);
                cand[base]     = b1;
                cand[base + 1] = b2;
            }
        }
    }
}

// ---------------- refine: exact fp32 chain (round-1 semantics) on survivors
__global__ void __launch_bounds__(256)
vq_refine(const float* __restrict__ z, const float* __restrict__ cb,
          const float* __restrict__ A, const u64* __restrict__ cand,
          int* __restrict__ bestIdx) {
    __shared__ float zs[4][DIM];
    __shared__ int   sc[4][128];
    int w = threadIdx.x >> 6, lane = threadIdx.x & 63;
    int row = blockIdx.x * 4 + w;

    const float* zr = z + (size_t)row * DIM;
    *(float4*)&zs[w][lane * 4]       = *(const float4*)(zr + lane * 4);
    *(float4*)&zs[w][256 + lane * 4] = *(const float4*)(zr + 256 + lane * 4);

    const u64* cr = cand + ((size_t)row << 7);
    u64 c0 = cr[lane * 2], c1 = cr[lane * 2 + 1];
    u64 mn = c0 < c1 ? c0 : c1;
    #pragma unroll
    for (int m = 32; m > 0; m >>= 1) { u64 o = __shfl_xor(mn, m); if (o < mn) mn = o; }
    float minD = __uint_as_float((unsigned)(mn >> 32));
    float thr = minD + 2e-4f;
    bool s0 = __uint_as_float((unsigned)(c0 >> 32)) <= thr;
    bool s1 = __uint_as_float((unsigned)(c1 >> 32)) <= thr;
    u64 m0 = __ballot(s0), m1 = __ballot(s1);
    u64 below = ((u64)1 << lane) - 1;
    int n0 = __popcll(m0);
    if (s0) sc[w][__popcll(m0 & below)]      = (int)(unsigned)c0;
    if (s1) sc[w][n0 + __popcll(m1 & below)] = (int)(unsigned)c1;
    int ns = n0 + __popcll(m1);
    __syncthreads();

    float Arow = A[row];
    u64 best = ~0ull;
    for (int j = lane; j < ns; j += 64) {
        int col = sc[w][j];
        const float* e = cb + (size_t)col * DIM;
        float acc2 = 0.0f;
        for (int k = 0; k < DIM; ++k) acc2 = fmaf(zs[w][k], e[k], acc2);
        float d = Arow - 2.0f * acc2;
        u64 p = ((u64)__float_as_uint(d) << 32) | (unsigned)col;
        if (p < best) best = p;
    }
    #pragma unroll
    for (int m = 32; m > 0; m >>= 1) { u64 o = __shfl_xor(best, m); if (o < best) best = o; }
    if (lane == 0) bestIdx[row] = (int)(unsigned)best;
}

// ------------------------- gather, STE out, loss rows (round-1 semantics)
__global__ void __launch_bounds__(256)
vq_gather(const float* __restrict__ z, const float* __restrict__ cb,
          const int* __restrict__ bestIdx, float* __restrict__ outQ,
          float* __restrict__ outIdx, double* __restrict__ lossRow) {
    int w = threadIdx.x >> 6, lane = threadIdx.x & 63;
    int row = blockIdx.x * 4 + w;
    int bi = bestIdx[row];
    const float* q  = cb + (size_t)bi * DIM;
    const float* zr = z  + (size_t)row * DIM;
    float* o = outQ + (size_t)row * DIM;
    double ls = 0.0;
    #pragma unroll
    for (int j = 0; j < 2; ++j) {
        int off = j * 256 + lane * 4;
        float4 qv = *(const float4*)(q  + off);
        float4 zv = *(const float4*)(zr + off);
        float t0 = qv.x - zv.x, t1 = qv.y - zv.y;
        float t2 = qv.z - zv.z, t3 = qv.w - zv.w;
        float4 ov = { zv.x + t0, zv.y + t1, zv.z + t2, zv.w + t3 };
        *(float4*)(o + off) = ov;
        ls += (double)t0 * t0 + (double)t1 * t1
            + (double)t2 * t2 + (double)t3 * t3;
    }
    #pragma unroll
    for (int off = 32; off > 0; off >>= 1) ls += __shfl_down(ls, off, 64);
    if (lane == 0) { lossRow[row] = ls; outIdx[row] = (float)bi; }
}

__global__ void __launch_bounds__(256)
vq_loss_final(const double* __restrict__ lossRow, float* __restrict__ outLoss) {
    __shared__ double sm[256];
    double s = 0.0;
    for (int i = threadIdx.x; i < M_ROWS; i += 256) s += lossRow[i];
    sm[threadIdx.x] = s;
    __syncthreads();
    for (int st = 128; st > 0; st >>= 1) {
        if (threadIdx.x < st) sm[threadIdx.x] += sm[threadIdx.x + st];
        __syncthreads();
    }
    if (threadIdx.x == 0)
        outLoss[0] = (float)(1.25 * sm[0] / (double)((size_t)M_ROWS * DIM));
}

extern "C" void kernel_launch(void* const* d_in, const int* in_sizes, int n_in,
                              void* d_out, int out_size, void* d_ws, size_t ws_size,
                              hipStream_t stream) {
    const float* z  = (const float*)d_in[0];
    const float* cb = (const float*)d_in[1];

    float* out     = (float*)d_out;
    float* outQ    = out;
    float* outIdx  = out + (size_t)M_ROWS * DIM;
    float* outLoss = out + (size_t)M_ROWS * DIM + M_ROWS;

    // zh lives in d_out scratch (overwritten later by gather)
    _Float16* zh = (_Float16*)d_out;

    char* ws = (char*)d_ws;
    float*  A       = (float*)ws;            ws += (size_t)M_ROWS * 4;
    double* lossRow = (double*)ws;           ws += (size_t)M_ROWS * 8;
    int*    bestIdx = (int*)ws;              ws += (size_t)M_ROWS * 4;
    _Float16* eh    = (_Float16*)ws;         ws += (size_t)KCB * DIM * 2;
    u64*    cand    = (u64*)ws;              // 32768*128*8 = 33.5 MB

    hipLaunchKernelGGL(vq_split_hi, dim3(M_ROWS * DIM / 4 / 256), dim3(256), 0, stream,
                       z, zh, 1.0f, M_ROWS * DIM / 4);
    hipLaunchKernelGGL(vq_split_hi, dim3(KCB * DIM / 4 / 256), dim3(256), 0, stream,
                       cb, eh, 4096.0f, KCB * DIM / 4);
    hipLaunchKernelGGL(vq_rownorm, dim3(M_ROWS / 4), dim3(256), 0, stream, z, A);
    hipLaunchKernelGGL(vq_gemm, dim3((M_ROWS / BM) * (KCB / BN)), dim3(512), 0, stream,
                       zh, eh, A, cand);
    hipLaunchKernelGGL(vq_refine, dim3(M_ROWS / 4), dim3(256), 0, stream,
                       z, cb, A, cand, bestIdx);
    hipLaunchKernelGGL(vq_gather, dim3(M_ROWS / 4), dim3(256), 0, stream,
                       z, cb, bestIdx, outQ, outIdx, lossRow);
    hipLaunchKernelGGL(vq_loss_final, dim3(1), dim3(256), 0, stream, lossRow, outLoss);
}

// Round 4
// 642.231 us; speedup vs baseline: 5.9529x; 1.1159x over previous
//
#include <hip/hip_runtime.h>

#define M_ROWS 32768
#define DIM    512
#define KCB    8192
#define BM     256
#define BN     256
#define NKS    16          // K-steps of 32
#define NSLAB  128         // 64-col slabs per row

typedef _Float16 f16x8 __attribute__((ext_vector_type(8)));
typedef float    f32x4 __attribute__((ext_vector_type(4)));
typedef unsigned long long u64;

#define AS1(p) ((const __attribute__((address_space(1))) void*)(p))
#define AS3(p) ((__attribute__((address_space(3))) void*)(p))

// -------- pack fp16 hi-plane into MFMA 16x16x32 fragment order --------------
// frag unit u: lane l = u&63, g = (u>>6)&15, s = (u>>10)&15, rb = u>>14
// holds (row = rb*256 + g*16 + (l&15), k = s*32 + (l>>4)*8 .. +8)
__global__ void __launch_bounds__(256)
vq_fragpack(const float* __restrict__ x, _Float16* __restrict__ dst,
            float scale, int nfr) {
    int u = blockIdx.x * 256 + threadIdx.x;
    if (u >= nfr) return;
    int l  = u & 63;
    int g  = (u >> 6) & 15;
    int s  = (u >> 10) & 15;
    int rb = u >> 14;
    int row = rb * 256 + g * 16 + (l & 15);
    int k   = s * 32 + (l >> 4) * 8;
    const float* src = x + (size_t)row * DIM + k;
    float4 v0 = *(const float4*)src;
    float4 v1 = *(const float4*)(src + 4);
    f16x8 h = { (_Float16)(v0.x*scale), (_Float16)(v0.y*scale),
                (_Float16)(v0.z*scale), (_Float16)(v0.w*scale),
                (_Float16)(v1.x*scale), (_Float16)(v1.y*scale),
                (_Float16)(v1.z*scale), (_Float16)(v1.w*scale) };
    *(f16x8*)((char*)dst + (size_t)u * 16) = h;
}

// ---------------------------------------------------------------- row norms
__global__ void __launch_bounds__(256) vq_rownorm(const float* __restrict__ z,
                                                  float* __restrict__ A) {
    int row  = blockIdx.x * 4 + (threadIdx.x >> 6);
    int lane = threadIdx.x & 63;
    const float* zr = z + (size_t)row * DIM;
    float4 a = *(const float4*)(zr + lane * 4);
    float4 b = *(const float4*)(zr + 256 + lane * 4);
    float s = a.x*a.x + a.y*a.y + a.z*a.z + a.w*a.w
            + b.x*b.x + b.y*b.y + b.z*b.z + b.w*b.w;
    #pragma unroll
    for (int off = 32; off > 0; off >>= 1) s += __shfl_down(s, off, 64);
    if (lane == 0) A[row] = s;
}

// ------- counted-vmcnt 4-buffer pipelined f16 MFMA GEMM + top-2 select ------
__global__ void __launch_bounds__(512, 2)
vq_gemm(const _Float16* __restrict__ zf, const _Float16* __restrict__ ef,
        const float* __restrict__ A, u64* __restrict__ cand) {
    extern __shared__ char lds[];          // 4 buffers x (A 16KB | B 16KB)
    const int tid  = threadIdx.x;
    const int lane = tid & 63;
    const int wid  = tid >> 6;
    const int wm   = wid >> 2;             // 0..1 -> 128-row half
    const int wn   = wid & 3;              // 0..3 -> 64-col quarter
    const int rb   = (int)blockIdx.x >> 5;
    const int cbk  = (int)blockIdx.x & 31;
    const char* zsrc = (const char*)zf + ((size_t)rb  << 18);  // 16 steps * 16KB
    const char* esrc = (const char*)ef + ((size_t)cbk << 18);

    f32x4 acc[8][4];
    #pragma unroll
    for (int m = 0; m < 8; ++m)
        #pragma unroll
        for (int n = 0; n < 4; ++n) acc[m][n] = (f32x4)0.0f;

    auto STAGE = [&](int t) {
        char* dst = lds + ((t & 3) << 15);
        #pragma unroll
        for (int j = 0; j < 4; ++j) {
            int n = (wid << 2) | j;        // 0..31: 0-15 A frags, 16-31 B frags
            const char* src = (n < 16)
                ? zsrc + ((size_t)t << 14) + ((size_t)n << 10) + (lane << 4)
                : esrc + ((size_t)t << 14) + ((size_t)(n - 16) << 10) + (lane << 4);
            __builtin_amdgcn_global_load_lds(AS1(src), AS3(dst + (n << 10)), 16, 0, 0);
        }
    };

    auto COMPUTE = [&](int t) {
        const char* bufA = lds + ((t & 3) << 15);
        const char* bufB = bufA + 16384;
        f16x8 af[8];
        #pragma unroll
        for (int m = 0; m < 8; ++m)
            af[m] = *(const f16x8*)(bufA + (((wm << 3) | m) << 10) + (lane << 4));
        f16x8 b0 = *(const f16x8*)(bufB + (((wn << 2) | 0) << 10) + (lane << 4));
        f16x8 b1 = *(const f16x8*)(bufB + (((wn << 2) | 1) << 10) + (lane << 4));
        __builtin_amdgcn_s_setprio(1);
        #pragma unroll
        for (int m = 0; m < 8; ++m) {
            acc[m][0] = __builtin_amdgcn_mfma_f32_16x16x32_f16(af[m], b0, acc[m][0], 0, 0, 0);
            acc[m][1] = __builtin_amdgcn_mfma_f32_16x16x32_f16(af[m], b1, acc[m][1], 0, 0, 0);
        }
        __builtin_amdgcn_s_setprio(0);
        f16x8 b2 = *(const f16x8*)(bufB + (((wn << 2) | 2) << 10) + (lane << 4));
        f16x8 b3 = *(const f16x8*)(bufB + (((wn << 2) | 3) << 10) + (lane << 4));
        __builtin_amdgcn_s_setprio(1);
        #pragma unroll
        for (int m = 0; m < 8; ++m) {
            acc[m][2] = __builtin_amdgcn_mfma_f32_16x16x32_f16(af[m], b2, acc[m][2], 0, 0, 0);
            acc[m][3] = __builtin_amdgcn_mfma_f32_16x16x32_f16(af[m], b3, acc[m][3], 0, 0, 0);
        }
        __builtin_amdgcn_s_setprio(0);
    };

    // prologue: 3 buffers in flight, retire buf0
    STAGE(0); STAGE(1); STAGE(2);
    asm volatile("s_waitcnt vmcnt(8)" ::: "memory");
    asm volatile("s_barrier" ::: "memory");
    __builtin_amdgcn_sched_barrier(0);

    for (int t = 0; t < 13; ++t) {
        STAGE(t + 3);                       // outstanding: t+1,t+2,t+3 = 12
        COMPUTE(t);
        asm volatile("s_waitcnt vmcnt(8) lgkmcnt(0)" ::: "memory");  // retire t+1
        asm volatile("s_barrier" ::: "memory");
        __builtin_amdgcn_sched_barrier(0);
    }
    COMPUTE(13);
    asm volatile("s_waitcnt vmcnt(4) lgkmcnt(0)" ::: "memory");      // retire 14
    asm volatile("s_barrier" ::: "memory");
    __builtin_amdgcn_sched_barrier(0);
    COMPUTE(14);
    asm volatile("s_waitcnt vmcnt(0) lgkmcnt(0)" ::: "memory");      // retire 15
    asm volatile("s_barrier" ::: "memory");
    __builtin_amdgcn_sched_barrier(0);
    COMPUTE(15);
    __syncthreads();

    // epilogue: d = A - acc/2048, top-2 per row over this wave's 64 cols
    float* As = (float*)lds;
    if (tid < BM) As[tid] = A[rb * BM + tid];
    __syncthreads();

    #pragma unroll
    for (int m = 0; m < 8; ++m) {
        #pragma unroll
        for (int rg = 0; rg < 4; ++rg) {
            int row_l = (wm << 7) + (m << 4) + ((lane >> 4) << 2) + rg;
            float Arow = As[row_l];
            u64 b1v = ~0ull, b2v = ~0ull;
            #pragma unroll
            for (int n = 0; n < 4; ++n) {
                float d = Arow - acc[m][n][rg] * (1.0f / 2048.0f);
                int col = (cbk << 8) + (wn << 6) + (n << 4) + (lane & 15);
                u64 p = ((u64)__float_as_uint(d) << 32) | (unsigned)col;
                if (p < b1v) { b2v = b1v; b1v = p; } else if (p < b2v) b2v = p;
            }
            #pragma unroll
            for (int mk = 1; mk < 16; mk <<= 1) {
                u64 o1 = __shfl_xor(b1v, mk);
                u64 o2 = __shfl_xor(b2v, mk);
                u64 lo = b1v < o1 ? b1v : o1;
                u64 hi = b1v < o1 ? o1 : b1v;
                u64 so = b2v < o2 ? b2v : o2;
                b1v = lo; b2v = hi < so ? hi : so;
            }
            if ((lane & 15) == 0) {
                size_t base = (size_t)(rb * BM + row_l) * (2 * NSLAB)
                            + (size_t)(((cbk << 2) | wn) << 1);
                cand[base]     = b1v;
                cand[base + 1] = b2v;
            }
        }
    }
}

// ---------------- refine: exact fp32 chain (round-1 semantics) on survivors
__global__ void __launch_bounds__(256)
vq_refine(const float* __restrict__ z, const float* __restrict__ cb,
          const float* __restrict__ A, const u64* __restrict__ cand,
          int* __restrict__ bestIdx) {
    __shared__ float zs[4][DIM];
    __shared__ int   sc[4][128];
    int w = threadIdx.x >> 6, lane = threadIdx.x & 63;
    int row = blockIdx.x * 4 + w;

    const float* zr = z + (size_t)row * DIM;
    *(float4*)&zs[w][lane * 4]       = *(const float4*)(zr + lane * 4);
    *(float4*)&zs[w][256 + lane * 4] = *(const float4*)(zr + 256 + lane * 4);

    const u64* cr = cand + (size_t)row * (2 * NSLAB);
    u64 c[4];
    #pragma unroll
    for (int k = 0; k < 4; ++k) c[k] = cr[lane * 4 + k];
    u64 mn = c[0];
    #pragma unroll
    for (int k = 1; k < 4; ++k) if (c[k] < mn) mn = c[k];
    #pragma unroll
    for (int m = 32; m > 0; m >>= 1) { u64 o = __shfl_xor(mn, m); if (o < mn) mn = o; }
    float minD = __uint_as_float((unsigned)(mn >> 32));
    float thr = minD + 2e-4f;
    u64 below = ((u64)1 << lane) - 1;
    int base = 0;
    #pragma unroll
    for (int k = 0; k < 4; ++k) {
        bool sk = __uint_as_float((unsigned)(c[k] >> 32)) <= thr;
        u64 mk = __ballot(sk);
        if (sk) {
            int slot = base + __popcll(mk & below);
            if (slot < 128) sc[w][slot] = (int)(unsigned)c[k];
        }
        base += __popcll(mk);
    }
    int ns = base < 128 ? base : 128;
    __syncthreads();

    float Arow = A[row];
    u64 best = ~0ull;
    for (int j = lane; j < ns; j += 64) {
        int col = sc[w][j];
        const float* e = cb + (size_t)col * DIM;
        float acc2 = 0.0f;
        for (int k = 0; k < DIM; ++k) acc2 = fmaf(zs[w][k], e[k], acc2);
        float d = Arow - 2.0f * acc2;
        u64 p = ((u64)__float_as_uint(d) << 32) | (unsigned)col;
        if (p < best) best = p;
    }
    #pragma unroll
    for (int m = 32; m > 0; m >>= 1) { u64 o = __shfl_xor(best, m); if (o < best) best = o; }
    if (lane == 0) bestIdx[row] = (int)(unsigned)best;
}

// ------------------------- gather, STE out, loss rows
__global__ void __launch_bounds__(256)
vq_gather(const float* __restrict__ z, const float* __restrict__ cb,
          const int* __restrict__ bestIdx, float* __restrict__ outQ,
          float* __restrict__ outIdx, double* __restrict__ lossRow) {
    int w = threadIdx.x >> 6, lane = threadIdx.x & 63;
    int row = blockIdx.x * 4 + w;
    int bi = bestIdx[row];
    const float* q  = cb + (size_t)bi * DIM;
    const float* zr = z  + (size_t)row * DIM;
    float* o = outQ + (size_t)row * DIM;
    double ls = 0.0;
    #pragma unroll
    for (int j = 0; j < 2; ++j) {
        int off = j * 256 + lane * 4;
        float4 qv = *(const float4*)(q  + off);
        float4 zv = *(const float4*)(zr + off);
        float t0 = qv.x - zv.x, t1 = qv.y - zv.y;
        float t2 = qv.z - zv.z, t3 = qv.w - zv.w;
        float4 ov = { zv.x + t0, zv.y + t1, zv.z + t2, zv.w + t3 };
        *(float4*)(o + off) = ov;
        ls += (double)t0 * t0 + (double)t1 * t1
            + (double)t2 * t2 + (double)t3 * t3;
    }
    #pragma unroll
    for (int off = 32; off > 0; off >>= 1) ls += __shfl_down(ls, off, 64);
    if (lane == 0) { lossRow[row] = ls; outIdx[row] = (float)bi; }
}

__global__ void __launch_bounds__(256)
vq_loss_final(const double* __restrict__ lossRow, float* __restrict__ outLoss) {
    __shared__ double sm[256];
    double s = 0.0;
    for (int i = threadIdx.x; i < M_ROWS; i += 256) s += lossRow[i];
    sm[threadIdx.x] = s;
    __syncthreads();
    for (int st = 128; st > 0; st >>= 1) {
        if (threadIdx.x < st) sm[threadIdx.x] += sm[threadIdx.x + st];
        __syncthreads();
    }
    if (threadIdx.x == 0)
        outLoss[0] = (float)(1.25 * sm[0] / (double)((size_t)M_ROWS * DIM));
}

extern "C" void kernel_launch(void* const* d_in, const int* in_sizes, int n_in,
                              void* d_out, int out_size, void* d_ws, size_t ws_size,
                              hipStream_t stream) {
    const float* z  = (const float*)d_in[0];
    const float* cb = (const float*)d_in[1];

    float* out     = (float*)d_out;
    float* outQ    = out;
    float* outIdx  = out + (size_t)M_ROWS * DIM;
    float* outLoss = out + (size_t)M_ROWS * DIM + M_ROWS;

    // fragment-ordered z planes live in d_out scratch (overwritten by gather)
    _Float16* zfrag = (_Float16*)d_out;                    // 32 MB

    char* ws = (char*)d_ws;
    float*  A       = (float*)ws;            ws += (size_t)M_ROWS * 4;
    double* lossRow = (double*)ws;           ws += (size_t)M_ROWS * 8;
    int*    bestIdx = (int*)ws;              ws += (size_t)M_ROWS * 4;
    _Float16* efrag = (_Float16*)ws;         ws += (size_t)KCB * DIM * 2;    // 8 MB
    u64*    cand    = (u64*)ws;              // 32768*256*8 = 67 MB

    int nfr_z = M_ROWS * DIM / 8;            // 2097152
    int nfr_e = KCB * DIM / 8;               // 524288
    hipLaunchKernelGGL(vq_fragpack, dim3(nfr_z / 256), dim3(256), 0, stream,
                       z, zfrag, 1.0f, nfr_z);
    hipLaunchKernelGGL(vq_fragpack, dim3(nfr_e / 256), dim3(256), 0, stream,
                       cb, efrag, 4096.0f, nfr_e);
    hipLaunchKernelGGL(vq_rownorm, dim3(M_ROWS / 4), dim3(256), 0, stream, z, A);
    hipLaunchKernelGGL(vq_gemm, dim3((M_ROWS / BM) * (KCB / BN)), dim3(512),
                       131072, stream, zfrag, efrag, A, cand);
    hipLaunchKernelGGL(vq_refine, dim3(M_ROWS / 4), dim3(256), 0, stream,
                       z, cb, A, cand, bestIdx);
    hipLaunchKernelGGL(vq_gather, dim3(M_ROWS / 4), dim3(256), 0, stream,
                       z, cb, bestIdx, outQ, outIdx, lossRow);
    hipLaunchKernelGGL(vq_loss_final, dim3(1), dim3(256), 0, stream, lossRow, outLoss);
}